// Round 7
// baseline (285.772 us; speedup 1.0000x reference)
//
#include <hip/hip_runtime.h>
#include <math.h>

#define NN 1024
#define BATCH 32
#define P 16              // pipeline stages per batch (64 rows each, 1 row/lane)
#define NWB 4             // waves per block = 4 independent batches, same stage
#define THREADS 256
#define NBLK 128          // P * 8 XCD-groups
#define DD 32             // diagonals per interval
#define NT 64             // DD*NT = 2048 >= 2047 diagonals
#define RB 4              // fabric ring slots per interface (power of 2)
#define WLN 2176          // stage-p weight LUT length (idx = kbase+d-2*lane+128)
#define GW 0.05f
#define K2 144.2695040888963f            // (1/gamma)*log2(e): scaled domain
#define INV_K2 0.0069314718055994531f    // gamma*ln2
#define BIGS 1.4426950408889634e11f      // 1e9 * K2

#define EXP2F(x) __builtin_amdgcn_exp2f(x)
#define LOG2F(x) __builtin_amdgcn_logf(x)   // v_log_f32 = log2

typedef unsigned long long u64;

// lanes 1..63 <- src[lane-1]; lane 0 <- oldv[0] (DPP wave_shr:1, bound_ctrl=false)
__device__ __forceinline__ float dppshr(float oldv, float src) {
    return __int_as_float(__builtin_amdgcn_update_dpp(
        __float_as_int(oldv), __float_as_int(src), 0x138, 0xF, 0xF, false));
}

// self-validating packet: {f32 value | u32 tag} in one atomic u64
__device__ __forceinline__ u64 pk(float v, unsigned tag) {
    return ((u64)tag << 32) | (u64)__float_as_uint(v);
}

// zero acks[512] + all packet words (tags must not alias across runs)
// gx = 512 interfaces * RB * DD = 65536 u64 -> 256 blocks; acks -> 2 blocks
__global__ __launch_bounds__(256) void ws_init(int* __restrict__ acks,
                                               u64* __restrict__ gx) {
    const int bid = blockIdx.x;
    if (bid < 256) gx[(size_t)bid * 256 + threadIdx.x] = 0;
    else acks[(bid - 256) * 256 + threadIdx.x] = 0;
}

// One DP step, 1 row/lane. Boundary stream feeds lane 0 via bnd1 (B[d-1]) in
// the up-dpp; dg comes from the dgp=up carry (lane 0: B[d-2] automatically).
// DOMASK is compile-time 0/1; entry mask doubles as R(i,-1)=inf. Cells with
// j>1023 compute finite garbage that only ever feeds other j>1023 cells.
#define STEPBODY(d, DOMASK) do {                                              \
        xv = dppshr(xin[(d)], xv);                  /* x[k-i] flows diag */   \
        const float up = dppshr(bnd1, r1);          /* R(i-1,k-1) */          \
        const float dg = dgp;                       /* R(i-1,k-2) */          \
        const float left = r1;                      /* R(i,  k-1) */          \
        const float diff = ti - xv;                                           \
        const float dk = diff * diff * wreg[(d)];   /* K2-scaled cost */      \
        const float mn = fminf(fminf(dg, up), left);                          \
        const float md = __builtin_amdgcn_fmed3f(dg, up, left);               \
        const float mx = fmaxf(fmaxf(dg, up), left);                          \
        const float ss = 1.0f + EXP2F(mn - md) + EXP2F(mn - mx);              \
        float r = dk + mn - LOG2F(ss);                                        \
        if (DOMASK) r = (jj0 >= -(d)) ? r : BIGS;   /* entry-side mask */     \
        r2 = r1; r1 = r; dgp = up; bnd1 = bd[(d)];                            \
        *(float*)((char*)wptr + (wmsk & (unsigned)((d) * 4))) = r1;           \
    } while (0)

// Boundary-stream wavefront soft-DTW, 16 stages x 64 rows, 1 row/lane.
// Round-11: R4-R6 falsified every sync-protocol theory for the 4,350cy
// interval overhead -> it is the overlapped-band structure itself (row-window
// march forces 31-lane r1/r2 refresh + 24% redundant rows + staged handoff).
// New structure: each wave PERMANENTLY owns 64 rows; DP state never leaves
// registers. The only inter-stage data is the boundary-row stream R(64p-1,k):
// DD values/interval, published as one parallel tagged store (collected via
// per-step lane-63 LDS write), consumed via lane-0 DPP injection (bnd1 reg
// rotation; dgp=up carry gives B[d-2] for free). No intra-block sync at all:
// 4 waves/block are different batches sharing only the stage-p weight LUT.
__global__ __launch_bounds__(THREADS) void sdtw_pipe16(
        const float* __restrict__ inp, const float* __restrict__ tgt,
        float* __restrict__ partial, int* __restrict__ acks,
        u64* __restrict__ gx)
{
    __shared__ __align__(16) float xs[NWB][NN];
    __shared__ __align__(16) float wlu[WLN];
    __shared__ __align__(16) float pub[NWB][DD];    // lane-63 per-step stream
    __shared__ __align__(16) float barr[NWB][DD];   // inbound value transpose
    __shared__ float dmp[NWB][64];                  // write sink, lanes 0..62

    const int bid = blockIdx.x;
    const int g = bid & 7;           // XCD group: all stages of a batch share it
    const int p = bid >> 3;          // stage 0..15
    const int tid = threadIdx.x;
    const int w = tid >> 6;          // wave slot
    const int lane = tid & 63;
    const int b = g + 8 * w;         // batch 0..31

    // per-wave x staging
    for (int idx = lane; idx < NN; idx += 64) xs[w][idx] = inp[b * NN + idx];
    // stage-shared weight LUT: wlu[idx] = K2*sigma(GW*(|m-1023|-512)),
    // m = idx + mlo, mlo = 895-128p. idx(d) = kbase+d-2*lane+128 in [2,2175].
    // Out-of-range m only feeds masked/garbage cells (finite benign K2).
    const int mlo = 895 - 128 * p;
    for (int tdx = tid; tdx < WLN; tdx += THREADS) {
        int m = tdx + mlo;
        float val = K2;
        if ((unsigned)m <= 2046u)
            val = K2 / (1.0f + __expf(-GW * (fabsf((float)m - 1023.0f) - 512.0f)));
        wlu[tdx] = val;
    }

    const int i = 64 * p + lane;     // owned row (always valid)
    const float ti = tgt[b * NN + i];
    const float* xb = xs[w];

    float r1 = BIGS, r2 = BIGS;      // R(i,k-1), R(i,k-2), scaled by K2
    float dgp = (i == 0) ? 0.0f : BIGS;  // R(i-1,k-2) carry; R(-1,-1)=0
    float bnd1 = BIGS;               // B[k-1] boundary carry (lane 0 inject)
    float xv = 0.0f;                 // x[k-i] rotation register
    int ackC = 0;

    __syncthreads();                 // LUT ready; waves free-run from here

    const int fin = b * P + p;       // inbound interface (p>0)
    const int fout = fin + 1;        // outbound interface (p<P-1)
    u64* gout = gx + (size_t)fout * (RB * DD);
    const u64* ginb = gx + (size_t)fin * (RB * DD);
    const bool prod = (p < P - 1);
    const bool cons = (p > 0);

    // lane-63 publish pointer trick: lane 63 -> pub[w][d], others -> dmp sink
    float* wptr = (lane == 63) ? &pub[w][0] : &dmp[w][lane];
    const unsigned wmsk = (lane == 63) ? ~0u : 0u;

    u64 pf = 0;                      // consumer prefetch reg (slot 0, tag 1)
    if (cons && lane < DD)
        pf = __hip_atomic_load(&ginb[lane], __ATOMIC_RELAXED,
                               __HIP_MEMORY_SCOPE_AGENT);

    // interval-0 preloads (wreg: weights; xin: lane-0 x injection values)
    float wreg[DD], xin[DD], bd[DD];
    {
        const float* wp = &wlu[128 - 2 * lane];
        #pragma unroll
        for (int h = 0; h < DD / 2; ++h) {
            float2 w2 = *reinterpret_cast<const float2*>(&wp[2 * h]);
            wreg[2 * h] = w2.x; wreg[2 * h + 1] = w2.y;
        }
        // jb = 0 - 64p <= 0 -> base 0 (j<0 injections feed masked cells)
        #pragma unroll
        for (int h = 0; h < DD / 4; ++h) {
            float4 q = *reinterpret_cast<const float4*>(&xb[4 * h]);
            xin[4 * h] = q.x; xin[4 * h + 1] = q.y;
            xin[4 * h + 2] = q.z; xin[4 * h + 3] = q.w;
        }
    }

    for (int t = 0; t < NT; ++t) {
        const int kbase = t << 5;

        // ---- top: consumer validates inbound stream for this interval ----
        if (cons) {
            const u64* gslot = ginb + (size_t)(t & (RB - 1)) * DD;
            const unsigned expect = (unsigned)(t + 1);
            for (;;) {
                int ok = (lane < DD) ? ((unsigned)(pf >> 32) == expect) : 1;
                if (__all(ok)) break;
                if (lane < DD)
                    pf = __hip_atomic_load(&gslot[lane], __ATOMIC_RELAXED,
                                           __HIP_MEMORY_SCOPE_AGENT);
            }
            if (lane < DD) barr[w][lane] = __uint_as_float((unsigned)pf);
            // ack: control-dependent on validated tags (loads completed)
            if (lane == 0)
                __hip_atomic_store(&acks[fin], t + 1, __ATOMIC_RELAXED,
                                   __HIP_MEMORY_SCOPE_AGENT);
            #pragma unroll
            for (int h = 0; h < DD / 4; ++h) {   // broadcast reads -> bd[]
                float4 q = *reinterpret_cast<const float4*>(&barr[w][4 * h]);
                bd[4 * h] = q.x; bd[4 * h + 1] = q.y;
                bd[4 * h + 2] = q.z; bd[4 * h + 3] = q.w;
            }
        } else {
            #pragma unroll
            for (int d = 0; d < DD; ++d) bd[d] = BIGS;   // row -1 = inf
        }

        // ---- interval t compute (32 diagonal steps) ----
        const int jj0 = kbase - i;
        if (kbase >= 64 * p + 63) {
            #pragma unroll
            for (int d = 0; d < DD; ++d) STEPBODY(d, 0);
        } else {
            #pragma unroll
            for (int d = 0; d < DD; ++d) STEPBODY(d, 1);
        }

        // ---- bottom: publish stream, prefetch, preload next interval ----
        if (prod) {
            float bv = (lane < DD) ? pub[w][lane] : 0.0f;   // lgkm auto-wait
            if (t >= RB) {           // slot t&3 must be consumed (ack >= t-3)
                while (ackC < t - (RB - 1)) {
                    __builtin_amdgcn_s_sleep(1);
                    ackC = __hip_atomic_load(&acks[fout], __ATOMIC_RELAXED,
                                             __HIP_MEMORY_SCOPE_AGENT);
                }
            }
            if (lane < DD)
                __hip_atomic_store(&gout[(size_t)(t & (RB - 1)) * DD + lane],
                                   pk(bv, (unsigned)(t + 1)),
                                   __ATOMIC_RELAXED, __HIP_MEMORY_SCOPE_AGENT);
            // ack prefetch for the next gate; hides under next interval
            ackC = __hip_atomic_load(&acks[fout], __ATOMIC_RELAXED,
                                     __HIP_MEMORY_SCOPE_AGENT);
        }
        if (t == NT - 1) break;

        if (cons && lane < DD)       // prefetch next inbound slot
            pf = __hip_atomic_load(&ginb[(size_t)((t + 1) & (RB - 1)) * DD + lane],
                                   __ATOMIC_RELAXED, __HIP_MEMORY_SCOPE_AGENT);

        {   // next interval's weights + x injections (latency hides here)
            const int kn = kbase + DD;
            const float* wp = &wlu[kn + 128 - 2 * lane];
            #pragma unroll
            for (int h = 0; h < DD / 2; ++h) {
                float2 w2 = *reinterpret_cast<const float2*>(&wp[2 * h]);
                wreg[2 * h] = w2.x; wreg[2 * h + 1] = w2.y;
            }
            // jb multiples of 32: never straddles validity -> clamp is exact
            int jb = kn - 64 * p;
            int base = min(max(jb, 0), NN - DD);
            #pragma unroll
            for (int h = 0; h < DD / 4; ++h) {
                float4 q = *reinterpret_cast<const float4*>(&xb[base + 4 * h]);
                xin[4 * h] = q.x; xin[4 * h + 1] = q.y;
                xin[4 * h + 2] = q.z; xin[4 * h + 3] = q.w;
            }
        }
    }

    // after t=NT-1: r2 = R(i, 2046); cell (1023,1023) at p=15, lane 63
    if (p == P - 1 && lane == 63) partial[b] = r2 * INV_K2;
}

__global__ __launch_bounds__(64) void reduce_mean32(const float* __restrict__ partial,
                                                    float* __restrict__ out) {
    float v = (threadIdx.x < BATCH) ? partial[threadIdx.x] : 0.0f;
    #pragma unroll
    for (int off = 32; off > 0; off >>= 1) v += __shfl_down(v, off);
    if (threadIdx.x == 0) out[0] = v * (1.0f / (float)BATCH);
}

extern "C" void kernel_launch(void* const* d_in, const int* in_sizes, int n_in,
                              void* d_out, int out_size, void* d_ws, size_t ws_size,
                              hipStream_t stream) {
    const float* inp = (const float*)d_in[0];  // [B, N, 1]
    const float* tgt = (const float*)d_in[1];  // [B, N, 1]
    float* out = (float*)d_out;                // [1]

    float* partial = (float*)d_ws;                        // 32 floats
    int* acks  = (int*)((char*)d_ws + 128);               // 512 ints
    u64* gx    = (u64*)((char*)d_ws + 128 + 2048);        // 512*RB*DD u64 = 512KB

    ws_init<<<258, 256, 0, stream>>>(acks, gx);
    sdtw_pipe16<<<NBLK, THREADS, 0, stream>>>(inp, tgt, partial, acks, gx);
    reduce_mean32<<<1, 64, 0, stream>>>(partial, out);
}

// Round 8
// 225.552 us; speedup vs baseline: 1.2670x; 1.2670x over previous
//
#include <hip/hip_runtime.h>
#include <math.h>

#define NN 1024
#define BATCH 32
#define P 8               // blocks per batch
#define NW 4              // waves per block
#define THREADS 256
#define DD 32             // diagonals per interval (needs SW >= DD-1, SW+DD <= 65)
#define SW 32             // row stride between waves
#define SPAN 160          // (NW-1)*SW + 64
#define NT 64             // ceil(2047/DD)
#define RB 4              // fabric ring slots per interface (power of 2)
#define EXB 4             // LDS exchange ring slots (power of 2)
#define WLN 2368          // per-block unified weight LUT length (covers m-range + guards)
#define GW 0.05f
#define K2 144.2695040888963f            // (1/gamma)*log2(e): scaled domain
#define INV_K2 0.0069314718055994531f    // gamma*ln2
#define BIGS 1.4426950408889634e11f      // 1e9 * K2

#define EXP2F(x) __builtin_amdgcn_exp2f(x)
#define LOG2F(x) __builtin_amdgcn_logf(x)   // v_log_f32 = log2

typedef unsigned long long u64;

// lanes 1..63 <- src[lane-1]; lane 0 <- oldv[0] (DPP wave_shr:1, bound_ctrl=false)
__device__ __forceinline__ float dppshr(float oldv, float src) {
    return __int_as_float(__builtin_amdgcn_update_dpp(
        __float_as_int(oldv), __float_as_int(src), 0x138, 0xF, 0xF, false));
}

// self-validating packet: {f32 value | u32 tag} in one atomic u64
__device__ __forceinline__ u64 pk(float v, unsigned tag) {
    return ((u64)tag << 32) | (u64)__float_as_uint(v);
}

// acquire-poll an LDS progress counter until >= want
__device__ __forceinline__ void waitProg(int* fp, int want) {
    while (__hip_atomic_load(fp, __ATOMIC_ACQUIRE, __HIP_MEMORY_SCOPE_WORKGROUP) < want)
        __builtin_amdgcn_s_sleep(1);
}

// zero acks[256] + all packet words (tags must not alias across runs)
// gx = 256 interfaces * RB * DD * 2 = 65536 u64 -> 256 blocks of 256
__global__ __launch_bounds__(256) void ws_init(int* __restrict__ acks,
                                               u64* __restrict__ gx) {
    if (blockIdx.x == 256) acks[threadIdx.x] = 0;
    else gx[(size_t)blockIdx.x * 256 + threadIdx.x] = 0;
}

// One DP step. DOMASK is compile-time 0/1; entry mask doubles as the i<0
// boundary (R(-1,j)=inf), so the wave containing rows i<0 keeps it forever.
#define STEPBODY(d, DOMASK) do {                                              \
        xv = dppshr(((d) == 0) ? xf0 : xv, xv);     /* x[k-i] flows diag */   \
        const float up = dppshr(((d) == 0) ? bndUp : r1, r1); /* R(i-1,k-1)*/ \
        const float dg = dgp;                                                 \
        const float left = r1;                                                \
        const float diff = ti - xv;                                           \
        const float dk = diff * diff * wreg[(d)];   /* K2-scaled cost */      \
        const float mn = fminf(fminf(dg, up), left);                          \
        const float md = __builtin_amdgcn_fmed3f(dg, up, left);               \
        const float mx = fmaxf(fmaxf(dg, up), left);                          \
        const float ss = 1.0f + EXP2F(mn - md) + EXP2F(mn - mx);              \
        float r = dk + mn - LOG2F(ss);                                        \
        if (DOMASK) r = (jj0 >= -(d)) ? r : BIGS;   /* entry-side mask */     \
        r2 = r1; r1 = r; dgp = up;                                            \
    } while (0)

// Overlapped-band wavefront soft-DTW, 8 CUs per batch.
// Round-12: standing-skew fabric edge. Every structure R0-R7 shows the same
// ~4-5k cy/interval stall; all zero-slack blocking points self-regulate at
// the miss edge of the queue, stochastically paying the device-scope
// store->visible->load RT each interval. Fix: (a) producer publishes at the
// BOTTOM of interval t (tag t+1, finals ready there) -- one period earlier
// than R6; (b) consumer validates+stashes tag t+1 at ITS bottom of t into
// the same nr* registers the intra-block pre-read uses; the top-of-interval
// becomes a pure register merge for all waves. Blocking at the bottom
// enforces >=1 period of skew; RB=4 ring lets steady state drift to
// ack-gated (skew~3) where validates always hit. Sleep backoff on the
// validate fallback kills spin contention. Math identical to R3/R6.
__global__ __launch_bounds__(THREADS) void sdtw_pipe8(
        const float* __restrict__ inp, const float* __restrict__ tgt,
        float* __restrict__ partial, int* __restrict__ acks,
        u64* __restrict__ gx)
{
    __shared__ __align__(16) float xs[NN];
    __shared__ __align__(16) float wlu[WLN];
    __shared__ float2 exch[EXB][SPAN];
    __shared__ int prog[NW];

    const int bid = blockIdx.x;
    const int b = bid & 31;          // same-batch stages share an XCD (bid%8 = b%8)
    const int p = bid >> 5;
    const int tid = threadIdx.x;
    const int w = tid >> 6;
    const int lane = tid & 63;

    // unified LUT: wlu[idx] = K2*sigma(G*(|m-1023|-512)), m = idx + mlo.
    // Per-block m range: m = k - 2i + 1023, k in [0,2047], i in [128p-31,128p+128]
    // -> [767-256p, 3132-256p]; out-of-range m only feeds masked/unread cells
    // (finite benign value K2). mlo odd + m0 odd -> idx even -> 8B aligned.
    const int mlo = 767 - 256 * p;
    for (int tdx = tid; tdx < NN; tdx += THREADS)
        xs[tdx] = inp[b * NN + tdx];
    for (int tdx = tid; tdx < WLN; tdx += THREADS) {
        int m = tdx + mlo;
        float val = K2;
        if ((unsigned)m <= 2046u)
            val = K2 / (1.0f + __expf(-GW * (fabsf((float)m - 1023.0f) - 512.0f)));
        wlu[tdx] = val;
    }
    if (tid < NW) prog[tid] = -1;

    const int i = 128 * p - (DD - 1) + SW * w + lane;   // owned row (may be OOB)
    const int i0 = i - lane;                            // wave's base row
    const bool rowValid = (unsigned)i < (unsigned)NN;
    int ic = min(max(i, 0), NN - 1);
    const float ti = tgt[b * NN + ic];
    const int imask = rowValid ? i : 0x3FFFFFFF;        // forces jj0 very negative
    // weight index at step d: (t<<5) + wq + d, wq = 256 + 256p - 2i (even, in [0,318])
    const int wq = 256 + 256 * p - 2 * i;

    float r1 = BIGS, r2 = BIGS;             // R(i,k-1), R(i,k-2), scaled by K2
    float dgp = (i == 0) ? 0.0f : BIGS;     // R(i-1,k-2) carry; R(-1,-1)=0
    float bndUp = BIGS;                     // lane-0 'up' feed at interval start
    float xv = 0.0f;                        // x[k - i] rotation register
    int ackC = 0;

    __syncthreads();                        // full sync once: LDS init done

    const int fin = b * P + p;              // inbound interface (p>0)
    const int fout = fin + 1;               // outbound interface (p<P-1)
    u64* gout = gx + (size_t)fout * (RB * DD * 2);
    const u64* ginb = gx + (size_t)fin * (RB * DD * 2);

    const bool isProd = (w == NW - 1) && (p < P - 1);
    const bool isCons = (w == 0) && (p > 0);
    const bool hasIn = (w > 0) || (p > 0);

    u64 pfA = 0, pfB = 0, pfC0 = 0, pfC1 = 0;   // consumer prefetch regs
    float nr1 = 0.0f, nr2 = 0.0f, nbx = 0.0f, nby = 0.0f;  // inbound stash regs

    // ping-pong prefetch of the x rotation seeds for interval t=0
    int cP  = min(max(-1 - i, 0), NN - 1);
    int c0P = min(max(-i0, 0), NN - 1);
    float xpreA = xs[cP];       // -> xv init: x[kbase-1-i]
    float xpreB = xs[c0P];      // -> xf0:     x[kbase-i0]

    // loop-carried weight registers: preload interval t=0
    float wreg[DD];
    {
        const float* wp = &wlu[wq];
        #pragma unroll
        for (int h = 0; h < DD / 2; ++h) {
            float2 w2 = *reinterpret_cast<const float2*>(&wp[2 * h]);
            wreg[2 * h] = w2.x; wreg[2 * h + 1] = w2.y;
        }
    }

    // initial fabric prefetch: tag 1 lives in slot 1
    if (isCons) {
        const u64* gslot = ginb + (size_t)(1 & (RB - 1)) * (DD * 2);
        if (lane < DD - 1) {
            pfA = __hip_atomic_load((u64*)&gslot[(size_t)(lane + 1) * 2],
                                    __ATOMIC_RELAXED, __HIP_MEMORY_SCOPE_AGENT);
            pfB = __hip_atomic_load((u64*)&gslot[(size_t)(lane + 1) * 2 + 1],
                                    __ATOMIC_RELAXED, __HIP_MEMORY_SCOPE_AGENT);
        }
        if (lane == 0) {
            pfC0 = __hip_atomic_load((u64*)&gslot[0],
                                     __ATOMIC_RELAXED, __HIP_MEMORY_SCOPE_AGENT);
            pfC1 = __hip_atomic_load((u64*)&gslot[1],
                                     __ATOMIC_RELAXED, __HIP_MEMORY_SCOPE_AGENT);
        }
    }

    for (int t = 0; t < NT; ++t) {
        // ---- top: pure register merge (stash filled at bottom of t-1) ----
        if (t > 0) {
            if (hasIn) {
                if (lane < DD - 1) { r1 = nr1; r2 = nr2; }
                float nd = dppshr(0.0f, r2);
                if (lane == 0)           { bndUp = nbx; dgp = nby; }
                else if (lane <= DD - 2) dgp = nd;
            } else {
                bndUp = BIGS;   // p==0, w==0: true boundary
            }
        }

        // ---- interval t compute ----
        const int kbase = t << 5;
        const int jj0 = kbase - imask;                  // j at d=0 (or very negative)

        const float xf0 = xpreB;
        xv = xpreA;
        // issue next interval's x seeds now; full interval to complete
        { int cN  = min(max(kbase + DD - 1 - i, 0), NN - 1);
          int c0N = min(max(kbase + DD - i0, 0), NN - 1);
          xpreA = xs[cN]; xpreB = xs[c0N]; }

        if (i0 >= 0 && kbase >= i0 + 63) {
            // steady: every lane has j>=0 for all d; rows >1023 compute
            // garbage that is provably never consumed (dpp feeds upward only,
            // exch/cross-block publishes cover valid rows only)
            #pragma unroll
            for (int d = 0; d < DD; ++d) STEPBODY(d, 0);
        } else {
            #pragma unroll
            for (int d = 0; d < DD; ++d) STEPBODY(d, 1);
        }
        if (t == NT - 1) break;

        // ---- bottom of interval t ----
        // (1) fabric publish ASAP: interval-t finals (lanes 31..62), tag t+1
        if (isProd) {
            if (t >= RB) {                  // slot (t+1)&3: need ack >= t+1-RB
                while (ackC < t + 1 - RB) {
                    __builtin_amdgcn_s_sleep(1);
                    ackC = __hip_atomic_load(&acks[fout], __ATOMIC_RELAXED,
                                             __HIP_MEMORY_SCOPE_AGENT);
                }
            }
            if (lane >= DD - 1 && lane < 63) {
                u64* gq = gout + (size_t)((t + 1) & (RB - 1)) * (DD * 2)
                               + (size_t)(lane - (DD - 1)) * 2;
                __hip_atomic_store(&gq[0], pk(r1, (unsigned)(t + 1)),
                                   __ATOMIC_RELAXED, __HIP_MEMORY_SCOPE_AGENT);
                __hip_atomic_store(&gq[1], pk(r2, (unsigned)(t + 1)),
                                   __ATOMIC_RELAXED, __HIP_MEMORY_SCOPE_AGENT);
            }
            // ack prefetch for next gate; latency hides under next interval
            ackC = __hip_atomic_load(&acks[fout], __ATOMIC_RELAXED,
                                     __HIP_MEMORY_SCOPE_AGENT);
        }

        // (2) intra-block publish: fresh lanes only. Ring overwrite gate:
        // slot t&3 held t-4's finals; reader w+1 pre-read them at its
        // bottom-of-(t-4), strictly before it set prog[w+1]=t-3.
        if (w < NW - 1) {
            if (t >= EXB - 1) waitProg(&prog[w + 1], t - (EXB - 1));
            if (lane >= DD - 1)
                exch[t & (EXB - 1)][SW * w + lane] = make_float2(r1, r2);
        }
        // progress flag: release orders the exch writes (and prior reads)
        if (lane == 0)
            __hip_atomic_store(&prog[w], t, __ATOMIC_RELEASE,
                               __HIP_MEMORY_SCOPE_WORKGROUP);

        // (3) own preloads: next interval's weights (latency hides here)
        {
            const float* wp = &wlu[((t + 1) << 5) + wq];
            #pragma unroll
            for (int h = 0; h < DD / 2; ++h) {
                float2 w2 = *reinterpret_cast<const float2*>(&wp[2 * h]);
                wreg[2 * h] = w2.x; wreg[2 * h + 1] = w2.y;
            }
        }

        // (4) inbound stash for interval t+1
        if (w > 0) {
            // intra-block pre-read of neighbor's interval-t finals
            waitProg(&prog[w - 1], t);
            const int buf = t & (EXB - 1);
            if (lane < DD - 1) { float2 vv = exch[buf][SW * w + lane]; nr1 = vv.x; nr2 = vv.y; }
            float2 bv = exch[buf][SW * w - 1];
            nbx = bv.x; nby = bv.y;
        } else if (p > 0) {
            // fabric validate+stash: tag t+1, slot (t+1)&3. Blocking HERE
            // (not at use) enforces a standing >=1-period skew at this edge.
            const unsigned expect = (unsigned)(t + 1);
            const u64* gslot = ginb + (size_t)((t + 1) & (RB - 1)) * (DD * 2);
            for (;;) {
                int ok = 1;
                if (lane < DD - 1)
                    ok = ((unsigned)(pfA >> 32) == expect) &
                         ((unsigned)(pfB >> 32) == expect);
                if (lane == 0)
                    ok &= ((unsigned)(pfC0 >> 32) == expect) &
                          ((unsigned)(pfC1 >> 32) == expect);
                if (__all(ok)) break;
                __builtin_amdgcn_s_sleep(1);    // backoff: no fabric hammering
                if (lane < DD - 1) {
                    pfA = __hip_atomic_load((u64*)&gslot[(size_t)(lane + 1) * 2],
                                            __ATOMIC_RELAXED, __HIP_MEMORY_SCOPE_AGENT);
                    pfB = __hip_atomic_load((u64*)&gslot[(size_t)(lane + 1) * 2 + 1],
                                            __ATOMIC_RELAXED, __HIP_MEMORY_SCOPE_AGENT);
                }
                if (lane == 0) {
                    pfC0 = __hip_atomic_load((u64*)&gslot[0],
                                             __ATOMIC_RELAXED, __HIP_MEMORY_SCOPE_AGENT);
                    pfC1 = __hip_atomic_load((u64*)&gslot[1],
                                             __ATOMIC_RELAXED, __HIP_MEMORY_SCOPE_AGENT);
                }
            }
            if (lane < DD - 1) { nr1 = __uint_as_float((unsigned)pfA);
                                 nr2 = __uint_as_float((unsigned)pfB); }
            nbx = __uint_as_float((unsigned)pfC0);
            nby = __uint_as_float((unsigned)pfC1);
            // ack value data-depends on validated tag: cannot precede loads
            if (lane == 0)
                __hip_atomic_store(&acks[fin], (int)(pfC0 >> 32),
                                   __ATOMIC_RELAXED, __HIP_MEMORY_SCOPE_AGENT);
            // prefetch tag t+2 (slot (t+2)&3): a full interval of flight time
            const u64* gnxt = ginb + (size_t)((t + 2) & (RB - 1)) * (DD * 2);
            if (lane < DD - 1) {
                pfA = __hip_atomic_load((u64*)&gnxt[(size_t)(lane + 1) * 2],
                                        __ATOMIC_RELAXED, __HIP_MEMORY_SCOPE_AGENT);
                pfB = __hip_atomic_load((u64*)&gnxt[(size_t)(lane + 1) * 2 + 1],
                                        __ATOMIC_RELAXED, __HIP_MEMORY_SCOPE_AGENT);
            }
            if (lane == 0) {
                pfC0 = __hip_atomic_load((u64*)&gnxt[0],
                                         __ATOMIC_RELAXED, __HIP_MEMORY_SCOPE_AGENT);
                pfC1 = __hip_atomic_load((u64*)&gnxt[1],
                                         __ATOMIC_RELAXED, __HIP_MEMORY_SCOPE_AGENT);
            }
        }
    }

    // after t=NT-1: r2 = R(i, 2046); cell (1023,1023) is at i=1023 (p=7,w=3,lane=62)
    if (i == NN - 1) partial[b] = r2 * INV_K2;
}

__global__ __launch_bounds__(64) void reduce_mean32(const float* __restrict__ partial,
                                                    float* __restrict__ out) {
    float v = (threadIdx.x < BATCH) ? partial[threadIdx.x] : 0.0f;
    #pragma unroll
    for (int off = 32; off > 0; off >>= 1) v += __shfl_down(v, off);
    if (threadIdx.x == 0) out[0] = v * (1.0f / (float)BATCH);
}

extern "C" void kernel_launch(void* const* d_in, const int* in_sizes, int n_in,
                              void* d_out, int out_size, void* d_ws, size_t ws_size,
                              hipStream_t stream) {
    const float* inp = (const float*)d_in[0];  // [B, N, 1]
    const float* tgt = (const float*)d_in[1];  // [B, N, 1]
    float* out = (float*)d_out;                // [1]

    float* partial = (float*)d_ws;                        // 32 floats
    int* acks  = (int*)((char*)d_ws + 128);               // 256 ints
    u64* gx    = (u64*)((char*)d_ws + 2048);              // 256*RB*DD*2 u64 = 512KB

    ws_init<<<257, 256, 0, stream>>>(acks, gx);
    sdtw_pipe8<<<BATCH * P, THREADS, 0, stream>>>(inp, tgt, partial, acks, gx);
    reduce_mean32<<<1, 64, 0, stream>>>(partial, out);
}

// Round 9
// 204.676 us; speedup vs baseline: 1.3962x; 1.1020x over previous
//
#include <hip/hip_runtime.h>
#include <math.h>

#define NN 1024
#define BATCH 32
#define P 8               // blocks per batch
#define NW 4              // waves per block
#define THREADS 256
#define DD 32             // diagonals per interval (needs SW >= DD-1, SW+DD <= 65)
#define SW 32             // row stride between waves
#define SPAN 160          // (NW-1)*SW + 64
#define NT 64             // ceil(2047/DD)
#define RB 4              // fabric ring slots, in PAIRS (power of 2)
#define WLN 2368          // per-block unified weight LUT length (covers m-range + guards)
#define GW 0.05f
#define K2 144.2695040888963f            // (1/gamma)*log2(e): scaled domain
#define INV_K2 0.0069314718055994531f    // gamma*ln2
#define BIGS 1.4426950408889634e11f      // 1e9 * K2

#define EXP2F(x) __builtin_amdgcn_exp2f(x)
#define LOG2F(x) __builtin_amdgcn_logf(x)   // v_log_f32 = log2

typedef unsigned long long u64;

// lanes 1..63 <- src[lane-1]; lane 0 <- oldv[0] (DPP wave_shr:1, bound_ctrl=false)
__device__ __forceinline__ float dppshr(float oldv, float src) {
    return __int_as_float(__builtin_amdgcn_update_dpp(
        __float_as_int(oldv), __float_as_int(src), 0x138, 0xF, 0xF, false));
}

// self-validating packet: {f32 value | u32 tag} in one atomic u64
__device__ __forceinline__ u64 pk(float v, unsigned tag) {
    return ((u64)tag << 32) | (u64)__float_as_uint(v);
}

// zero acks[256] + all packet words (tags must not alias across runs)
// gx = 256 interfaces * RB * DD * 4 = 131072 u64 -> 512 blocks of 256
__global__ __launch_bounds__(256) void ws_init(int* __restrict__ acks,
                                               u64* __restrict__ gx) {
    if (blockIdx.x == 512) acks[threadIdx.x] = 0;
    else gx[(size_t)blockIdx.x * 256 + threadIdx.x] = 0;
}

// One DP step. DOMASK is compile-time 0/1; entry mask doubles as the i<0
// boundary (R(-1,j)=inf), so the wave containing rows i<0 keeps it forever.
#define STEPBODY(d, DOMASK) do {                                              \
        xv = dppshr(((d) == 0) ? xf0 : xv, xv);     /* x[k-i] flows diag */   \
        const float up = dppshr(((d) == 0) ? bndUp : r1, r1); /* R(i-1,k-1)*/ \
        const float dg = dgp;                                                 \
        const float left = r1;                                                \
        const float diff = ti - xv;                                           \
        const float dk = diff * diff * wreg[(d)];   /* K2-scaled cost */      \
        const float mn = fminf(fminf(dg, up), left);                          \
        const float md = __builtin_amdgcn_fmed3f(dg, up, left);               \
        const float mx = fmaxf(fmaxf(dg, up), left);                          \
        const float ss = 1.0f + EXP2F(mn - md) + EXP2F(mn - mx);              \
        float r = dk + mn - LOG2F(ss);                                        \
        if (DOMASK) r = (jj0 >= -(d)) ? r : BIGS;   /* entry-side mask */     \
        r2 = r1; r1 = r; dgp = up;                                            \
    } while (0)

// Overlapped-band wavefront soft-DTW, 8 CUs per batch.
// Round-13: paired fabric handoff on the R3 (best=157us) skeleton. Ledger
// R0-R8: every sync protocol lands 157-176 -> F ~ 4,350cy/interval is NOT
// sync-mechanism; but fabric event COUNT and the zero-margin publish/validate
// race were never varied. Now: producer buffers odd-interval finals in 2
// VGPRs and publishes a 2-interval pair (4 tagged u64/lane) at even tops;
// consumer validates once per pair (odd tops), stashes the second half in
// registers, register-merges at even tops. Pair completion forces a natural
// 2-period inter-stage lag -> the validate race disappears deterministically
// (data visible ~1 period before use). Fabric events/interval halved.
__global__ __launch_bounds__(THREADS) void sdtw_pipe8(
        const float* __restrict__ inp, const float* __restrict__ tgt,
        float* __restrict__ partial, int* __restrict__ acks,
        u64* __restrict__ gx)
{
    __shared__ __align__(16) float xs[NN];
    __shared__ __align__(16) float wlu[WLN];
    __shared__ float2 exch[2][SPAN];

    const int bid = blockIdx.x;
    const int b = bid & 31;          // same-batch stages share an XCD (bid%8 = b%8)
    const int p = bid >> 5;
    const int tid = threadIdx.x;
    const int w = tid >> 6;
    const int lane = tid & 63;

    // unified LUT: wlu[idx] = K2*sigma(G*(|m-1023|-512)), m = idx + mlo.
    // Per-block m range: m = k - 2i + 1023, k in [0,2047], i in [128p-31,128p+128]
    // -> [767-256p, 3132-256p]; out-of-range m only feeds masked/unread cells
    // (finite benign value K2). mlo odd + m0 odd -> idx even -> 8B aligned.
    const int mlo = 767 - 256 * p;
    for (int tdx = tid; tdx < NN; tdx += THREADS)
        xs[tdx] = inp[b * NN + tdx];
    for (int tdx = tid; tdx < WLN; tdx += THREADS) {
        int m = tdx + mlo;
        float val = K2;
        if ((unsigned)m <= 2046u)
            val = K2 / (1.0f + __expf(-GW * (fabsf((float)m - 1023.0f) - 512.0f)));
        wlu[tdx] = val;
    }

    const int i = 128 * p - (DD - 1) + SW * w + lane;   // owned row (may be OOB)
    const int i0 = i - lane;                            // wave's base row
    const bool rowValid = (unsigned)i < (unsigned)NN;
    int ic = min(max(i, 0), NN - 1);
    const float ti = tgt[b * NN + ic];
    const int imask = rowValid ? i : 0x3FFFFFFF;        // forces jj0 very negative
    // weight index at step d: (t<<5) + wq + d, wq = 256 + 256p - 2i (even, in [0,318])
    const int wq = 256 + 256 * p - 2 * i;

    float r1 = BIGS, r2 = BIGS;             // R(i,k-1), R(i,k-2), scaled by K2
    float dgp = (i == 0) ? 0.0f : BIGS;     // R(i-1,k-2) carry; R(-1,-1)=0
    float bndUp = BIGS;                     // lane-0 'up' feed at interval start
    float xv = 0.0f;                        // x[k - i] rotation register
    float bf1 = BIGS, bf2 = BIGS;           // producer odd-interval finals buffer
    int ackC = 0;

    __syncthreads();                        // full sync once: LDS init done

    const int fin = b * P + p;              // inbound interface (p>0)
    const int fout = fin + 1;               // outbound interface (p<P-1)
    u64* gout = gx + (size_t)fout * (RB * DD * 4);
    const u64* ginb = gx + (size_t)fin * (RB * DD * 4);

    const bool isProd = (w == NW - 1) && (p < P - 1);
    const bool isCons = (w == 0) && (p > 0);

    // consumer prefetch regs: pfa..pfd = own-row words (j=lane+1, words 0..3),
    // pba..pbd = boundary words (j=0, lane 0 only)
    u64 pfa = 0, pfb = 0, pfc = 0, pfd = 0;
    u64 pba = 0, pbb = 0, pbc = 0, pbd = 0;
    float nr1 = 0.0f, nr2 = 0.0f, nbx = 0.0f, nby = 0.0f;  // odd-half stash

    // ping-pong prefetch of the x rotation seeds for interval t=0
    int cP  = min(max(-1 - i, 0), NN - 1);
    int c0P = min(max(-i0, 0), NN - 1);
    float xpreA = xs[cP];       // -> xv init: x[kbase-1-i]
    float xpreB = xs[c0P];      // -> xf0:     x[kbase-i0]

    for (int t = 0; t < NT; ++t) {
        if (t > 0) {
            // ---- producer: buffer odd finals; publish pair at even tops ----
            // r1/r2 of lanes 31..62 hold interval t-1 finals here (refresh
            // below only touches lanes 0..30).
            if (isProd) {
                if (t & 1) { bf1 = r1; bf2 = r2; }      // u0 = t-1 finals
                const bool doPub = (!(t & 1) && t >= 2) || (t == NT - 1);
                if (doPub) {
                    const int pr = ((t & 1) ? (t - 1) : (t - 2)) >> 1;
                    if (pr >= RB) {                     // slot pr&3 free?
                        while (ackC < pr + 1 - RB) {
                            __builtin_amdgcn_s_sleep(1);
                            ackC = __hip_atomic_load(&acks[fout], __ATOMIC_RELAXED,
                                                     __HIP_MEMORY_SCOPE_AGENT);
                        }
                    }
                    if (lane >= DD - 1 && lane < 63) {
                        u64* gq = gout + (size_t)(pr & (RB - 1)) * (DD * 4)
                                       + (size_t)(lane - (DD - 1)) * 4;
                        const unsigned tg = (unsigned)(pr + 1);
                        __hip_atomic_store(&gq[0], pk(bf1, tg),
                                           __ATOMIC_RELAXED, __HIP_MEMORY_SCOPE_AGENT);
                        __hip_atomic_store(&gq[1], pk(bf2, tg),
                                           __ATOMIC_RELAXED, __HIP_MEMORY_SCOPE_AGENT);
                        __hip_atomic_store(&gq[2], pk(r1, tg),
                                           __ATOMIC_RELAXED, __HIP_MEMORY_SCOPE_AGENT);
                        __hip_atomic_store(&gq[3], pk(r2, tg),
                                           __ATOMIC_RELAXED, __HIP_MEMORY_SCOPE_AGENT);
                    }
                    // ack prefetch for next gate; hides under inner loop
                    ackC = __hip_atomic_load(&acks[fout], __ATOMIC_RELAXED,
                                             __HIP_MEMORY_SCOPE_AGENT);
                }
            }
            // ---- refresh stale lanes (0..30) + boundary feed ----
            if (w > 0) {
                const int buf = (t - 1) & 1;
                if (lane < DD - 1) { float2 vv = exch[buf][SW * w + lane]; r1 = vv.x; r2 = vv.y; }
                float2 bv = exch[buf][SW * w - 1];
                float nd = dppshr(0.0f, r2);
                if (lane == 0)           { bndUp = bv.x; dgp = bv.y; }
                else if (lane <= DD - 2) dgp = nd;
            } else if (p > 0) {
                if (t & 1) {
                    // odd top: validate pair pr=(t-1)/2 (4 words), merge u0,
                    // stash u1 for the next (even) top. No sleep in the spin.
                    const int pr = (t - 1) >> 1;
                    const unsigned expect = (unsigned)(pr + 1);
                    const u64* gslot = ginb + (size_t)(pr & (RB - 1)) * (DD * 4);
                    for (;;) {
                        int ok = 1;
                        if (lane < DD - 1)
                            ok = ((unsigned)(pfa >> 32) == expect) &
                                 ((unsigned)(pfb >> 32) == expect) &
                                 ((unsigned)(pfc >> 32) == expect) &
                                 ((unsigned)(pfd >> 32) == expect);
                        if (lane == 0)
                            ok &= ((unsigned)(pba >> 32) == expect) &
                                  ((unsigned)(pbb >> 32) == expect) &
                                  ((unsigned)(pbc >> 32) == expect) &
                                  ((unsigned)(pbd >> 32) == expect);
                        if (__all(ok)) break;
                        if (lane < DD - 1) {
                            const u64* q = &gslot[(size_t)(lane + 1) * 4];
                            pfa = __hip_atomic_load(&q[0], __ATOMIC_RELAXED, __HIP_MEMORY_SCOPE_AGENT);
                            pfb = __hip_atomic_load(&q[1], __ATOMIC_RELAXED, __HIP_MEMORY_SCOPE_AGENT);
                            pfc = __hip_atomic_load(&q[2], __ATOMIC_RELAXED, __HIP_MEMORY_SCOPE_AGENT);
                            pfd = __hip_atomic_load(&q[3], __ATOMIC_RELAXED, __HIP_MEMORY_SCOPE_AGENT);
                        }
                        if (lane == 0) {
                            pba = __hip_atomic_load(&gslot[0], __ATOMIC_RELAXED, __HIP_MEMORY_SCOPE_AGENT);
                            pbb = __hip_atomic_load(&gslot[1], __ATOMIC_RELAXED, __HIP_MEMORY_SCOPE_AGENT);
                            pbc = __hip_atomic_load(&gslot[2], __ATOMIC_RELAXED, __HIP_MEMORY_SCOPE_AGENT);
                            pbd = __hip_atomic_load(&gslot[3], __ATOMIC_RELAXED, __HIP_MEMORY_SCOPE_AGENT);
                        }
                    }
                    if (lane < DD - 1) {
                        r1 = __uint_as_float((unsigned)pfa);
                        r2 = __uint_as_float((unsigned)pfb);
                        nr1 = __uint_as_float((unsigned)pfc);
                        nr2 = __uint_as_float((unsigned)pfd);
                    }
                    float nd = dppshr(0.0f, r2);
                    if (lane == 0) {
                        bndUp = __uint_as_float((unsigned)pba);
                        dgp   = __uint_as_float((unsigned)pbb);
                        nbx   = __uint_as_float((unsigned)pbc);
                        nby   = __uint_as_float((unsigned)pbd);
                    } else if (lane <= DD - 2) dgp = nd;
                    // ack value data-depends on validated tag
                    if (lane == 0)
                        __hip_atomic_store(&acks[fin], (int)(pba >> 32),
                                           __ATOMIC_RELAXED, __HIP_MEMORY_SCOPE_AGENT);
                } else {
                    // even top: pure register merge from the stashed u1 half
                    if (lane < DD - 1) { r1 = nr1; r2 = nr2; }
                    float nd = dppshr(0.0f, r2);
                    if (lane == 0)           { bndUp = nbx; dgp = nby; }
                    else if (lane <= DD - 2) dgp = nd;
                }
            } else {
                bndUp = BIGS;   // p==0, w==0: true boundary
            }
        }

        // ---- interval t compute ----
        const int kbase = t << 5;
        const int jj0 = kbase - imask;                  // j at d=0 (or very negative)

        // preload this interval's 32 consecutive weights into registers
        const float* wp = &wlu[kbase + wq];
        float wreg[DD];
        #pragma unroll
        for (int h = 0; h < DD / 2; ++h) {
            float2 w2 = *reinterpret_cast<const float2*>(&wp[2 * h]);
            wreg[2 * h] = w2.x; wreg[2 * h + 1] = w2.y;
        }

        const float xf0 = xpreB;
        xv = xpreA;
        // issue next interval's x seeds now; full interval to complete
        { int cN  = min(max(kbase + DD - 1 - i, 0), NN - 1);
          int c0N = min(max(kbase + DD - i0, 0), NN - 1);
          xpreA = xs[cN]; xpreB = xs[c0N]; }

        if (i0 >= 0 && kbase >= i0 + 63) {
            // steady: every lane has j>=0 for all d; rows >1023 compute
            // garbage that is provably never consumed
            #pragma unroll
            for (int d = 0; d < DD; ++d) STEPBODY(d, 0);
        } else {
            #pragma unroll
            for (int d = 0; d < DD; ++d) STEPBODY(d, 1);
        }
        if (t == NT - 1) break;

        // intra-block publish: fresh lanes only (wave NW-1's slots are unread)
        if (w < NW - 1 && lane >= DD - 1)
            exch[t & 1][SW * w + lane] = make_float2(r1, r2);

        // consumer prefetch: pair pr=t/2 at even bottoms (validated at the
        // next odd top; producer published it ~2 periods earlier -> hit)
        if (isCons && !(t & 1)) {
            const int pr = t >> 1;
            const u64* gslot = ginb + (size_t)(pr & (RB - 1)) * (DD * 4);
            if (lane < DD - 1) {
                const u64* q = &gslot[(size_t)(lane + 1) * 4];
                pfa = __hip_atomic_load(&q[0], __ATOMIC_RELAXED, __HIP_MEMORY_SCOPE_AGENT);
                pfb = __hip_atomic_load(&q[1], __ATOMIC_RELAXED, __HIP_MEMORY_SCOPE_AGENT);
                pfc = __hip_atomic_load(&q[2], __ATOMIC_RELAXED, __HIP_MEMORY_SCOPE_AGENT);
                pfd = __hip_atomic_load(&q[3], __ATOMIC_RELAXED, __HIP_MEMORY_SCOPE_AGENT);
            }
            if (lane == 0) {
                pba = __hip_atomic_load(&gslot[0], __ATOMIC_RELAXED, __HIP_MEMORY_SCOPE_AGENT);
                pbb = __hip_atomic_load(&gslot[1], __ATOMIC_RELAXED, __HIP_MEMORY_SCOPE_AGENT);
                pbc = __hip_atomic_load(&gslot[2], __ATOMIC_RELAXED, __HIP_MEMORY_SCOPE_AGENT);
                pbd = __hip_atomic_load(&gslot[3], __ATOMIC_RELAXED, __HIP_MEMORY_SCOPE_AGENT);
            }
        }

        // LDS-only barrier: drain ds_writes, leave global ops in flight.
        asm volatile("s_waitcnt lgkmcnt(0)" ::: "memory");
        __builtin_amdgcn_s_barrier();
        asm volatile("" ::: "memory");
        __builtin_amdgcn_sched_barrier(0);
    }

    // after t=NT-1: r2 = R(i, 2046); cell (1023,1023) is at i=1023 (p=7,w=3,lane=62)
    if (i == NN - 1) partial[b] = r2 * INV_K2;
}

__global__ __launch_bounds__(64) void reduce_mean32(const float* __restrict__ partial,
                                                    float* __restrict__ out) {
    float v = (threadIdx.x < BATCH) ? partial[threadIdx.x] : 0.0f;
    #pragma unroll
    for (int off = 32; off > 0; off >>= 1) v += __shfl_down(v, off);
    if (threadIdx.x == 0) out[0] = v * (1.0f / (float)BATCH);
}

extern "C" void kernel_launch(void* const* d_in, const int* in_sizes, int n_in,
                              void* d_out, int out_size, void* d_ws, size_t ws_size,
                              hipStream_t stream) {
    const float* inp = (const float*)d_in[0];  // [B, N, 1]
    const float* tgt = (const float*)d_in[1];  // [B, N, 1]
    float* out = (float*)d_out;                // [1]

    float* partial = (float*)d_ws;                        // 32 floats
    int* acks  = (int*)((char*)d_ws + 128);               // 256 ints
    u64* gx    = (u64*)((char*)d_ws + 2048);              // 256*RB*DD*4 u64 = 1MB

    ws_init<<<513, 256, 0, stream>>>(acks, gx);
    sdtw_pipe8<<<BATCH * P, THREADS, 0, stream>>>(inp, tgt, partial, acks, gx);
    reduce_mean32<<<1, 64, 0, stream>>>(partial, out);
}